// Round 1
// baseline (6147.452 us; speedup 1.0000x reference)
//
#include <hip/hip_runtime.h>

// Problem constants (fixed by the reference)
#define BATCH 2048
#define TT    256
#define DD    128
#define HH    256
#define GG    768   // 3*H
#define PP    2048
#define RR    8     // batch rows per block

__device__ __forceinline__ float sigmoidf_(float v) { return 1.0f / (1.0f + expf(-v)); }

// Pre-transpose weights and prototypes for coalesced streaming.
// wTih: [DD][GG], wThh: [HH][GG], pT: [HH][PP]
__global__ void prep_kernel(const float* __restrict__ w_ih, const float* __restrict__ w_hh,
                            const float* __restrict__ protos,
                            float* __restrict__ wTih, float* __restrict__ wThh,
                            float* __restrict__ pT) {
    int i = blockIdx.x * blockDim.x + threadIdx.x;
    if (i < DD * GG) { int k = i / GG, g = i % GG; wTih[i] = w_ih[g * DD + k]; }
    if (i < HH * GG) { int k = i / GG, g = i % GG; wThh[i] = w_hh[g * HH + k]; }
    if (i < HH * PP) { int k = i / PP, p = i % PP; pT[i]   = protos[p * HH + k]; }
}

// One block = 8 batch rows for the full T=256 recurrence + cdist/argmin.
// Thread j (0..255) owns hidden unit j: computes gates r,z,n for unit j across
// all 8 rows each step. x/h live in LDS (k-major, read as uniform-address
// float4 broadcasts), weights stream coalesced from L2 (fit in 4MB XCD L2).
__launch_bounds__(256, 1)
__global__ void gru_kernel(const float* __restrict__ x,
                           const float* __restrict__ wTih, const float* __restrict__ wThh,
                           const float* __restrict__ b_ih, const float* __restrict__ b_hh,
                           const float* __restrict__ pT,
                           int* __restrict__ out) {
    __shared__ float xs[2][DD][RR];   // 8 KB, double-buffered x_t staging (k-major)
    __shared__ float hs[HH][RR];      // 8 KB, hidden state (k-major)
    __shared__ float rd[RR][256];     // 8 KB, argmin reduce (dist)
    __shared__ int   ri[RR][256];     // 8 KB, argmin reduce (index)

    const int tid  = threadIdx.x;     // hidden unit j
    const int row0 = blockIdx.x * RR;

    const float bxr = b_ih[tid], bxz = b_ih[HH + tid], bxn = b_ih[2 * HH + tid];
    const float bhr = b_hh[tid], bhz = b_hh[HH + tid], bhn = b_hh[2 * HH + tid];

    float hprev[RR];
    #pragma unroll
    for (int r = 0; r < RR; ++r) hprev[r] = 0.0f;
    #pragma unroll
    for (int r = 0; r < RR; ++r) hs[tid][r] = 0.0f;

    // x loader mapping: thread -> (row lr, 4 contiguous cols at lk)
    const int lr = tid >> 5;
    const int lk = (tid & 31) * 4;
    const float* xrow = x + (size_t)(row0 + lr) * TT * DD + lk;
    {
        float4 v = *(const float4*)(xrow);
        xs[0][lk + 0][lr] = v.x; xs[0][lk + 1][lr] = v.y;
        xs[0][lk + 2][lr] = v.z; xs[0][lk + 3][lr] = v.w;
    }
    __syncthreads();

    for (int t = 0; t < TT; ++t) {
        const int cur = t & 1, nxt = cur ^ 1;

        // prefetch next timestep's x into registers (hidden under the dots)
        float4 pf = make_float4(0.f, 0.f, 0.f, 0.f);
        if (t + 1 < TT) pf = *(const float4*)(xrow + (size_t)(t + 1) * DD);

        // ---- input projection: xp = x_t @ w_ih^T + b_ih (dot over D=128) ----
        float aR[RR], aZ[RR], aN[RR];
        #pragma unroll
        for (int r = 0; r < RR; ++r) { aR[r] = bxr; aZ[r] = bxz; aN[r] = bxn; }
        #pragma unroll 4
        for (int k = 0; k < DD; ++k) {
            const float wr = wTih[k * GG + tid];
            const float wz = wTih[k * GG + HH + tid];
            const float wn = wTih[k * GG + 2 * HH + tid];
            const float4 v0 = *(const float4*)&xs[cur][k][0];
            const float4 v1 = *(const float4*)&xs[cur][k][4];
            float vv[RR] = {v0.x, v0.y, v0.z, v0.w, v1.x, v1.y, v1.z, v1.w};
            #pragma unroll
            for (int r = 0; r < RR; ++r) {
                aR[r] += vv[r] * wr; aZ[r] += vv[r] * wz; aN[r] += vv[r] * wn;
            }
        }

        // ---- hidden projection: hp = h @ w_hh^T + b_hh (dot over H=256) ----
        float hR[RR], hZ[RR], hN[RR];
        #pragma unroll
        for (int r = 0; r < RR; ++r) { hR[r] = bhr; hZ[r] = bhz; hN[r] = bhn; }
        #pragma unroll 4
        for (int k = 0; k < HH; ++k) {
            const float wr = wThh[k * GG + tid];
            const float wz = wThh[k * GG + HH + tid];
            const float wn = wThh[k * GG + 2 * HH + tid];
            const float4 v0 = *(const float4*)&hs[k][0];
            const float4 v1 = *(const float4*)&hs[k][4];
            float vv[RR] = {v0.x, v0.y, v0.z, v0.w, v1.x, v1.y, v1.z, v1.w};
            #pragma unroll
            for (int r = 0; r < RR; ++r) {
                hR[r] += vv[r] * wr; hZ[r] += vv[r] * wz; hN[r] += vv[r] * wn;
            }
        }

        // ---- gates + state update (PyTorch GRU semantics) ----
        #pragma unroll
        for (int r = 0; r < RR; ++r) {
            const float rg = sigmoidf_(aR[r] + hR[r]);
            const float zg = sigmoidf_(aZ[r] + hZ[r]);
            const float ng = tanhf(aN[r] + rg * hN[r]);
            hprev[r] = (1.0f - zg) * ng + zg * hprev[r];
        }

        __syncthreads();  // all hs reads done before overwrite
        #pragma unroll
        for (int r = 0; r < RR; ++r) hs[tid][r] = hprev[r];
        if (t + 1 < TT) {
            xs[nxt][lk + 0][lr] = pf.x; xs[nxt][lk + 1][lr] = pf.y;
            xs[nxt][lk + 2][lr] = pf.z; xs[nxt][lk + 3][lr] = pf.w;
        }
        __syncthreads();
    }

    // ---- cdist^2 + argmin over P=2048 prototypes ----
    float best[RR]; int bidx[RR];
    #pragma unroll
    for (int r = 0; r < RR; ++r) { best[r] = 3.4e38f; bidx[r] = 0; }
    for (int m = 0; m < PP / 256; ++m) {
        float d2[RR];
        #pragma unroll
        for (int r = 0; r < RR; ++r) d2[r] = 0.0f;
        #pragma unroll 4
        for (int k = 0; k < HH; ++k) {
            const float pv = pT[k * PP + m * 256 + tid];
            const float4 v0 = *(const float4*)&hs[k][0];
            const float4 v1 = *(const float4*)&hs[k][4];
            float vv[RR] = {v0.x, v0.y, v0.z, v0.w, v1.x, v1.y, v1.z, v1.w};
            #pragma unroll
            for (int r = 0; r < RR; ++r) { const float df = vv[r] - pv; d2[r] += df * df; }
        }
        const int pidx = m * 256 + tid;
        #pragma unroll
        for (int r = 0; r < RR; ++r) {
            if (d2[r] < best[r]) { best[r] = d2[r]; bidx[r] = pidx; }  // ascending pidx per thread
        }
    }
    #pragma unroll
    for (int r = 0; r < RR; ++r) { rd[r][tid] = best[r]; ri[r][tid] = bidx[r]; }
    __syncthreads();
    for (int s = 128; s > 0; s >>= 1) {
        if (tid < s) {
            #pragma unroll
            for (int r = 0; r < RR; ++r) {
                const float da = rd[r][tid], db = rd[r][tid + s];
                const int   ia = ri[r][tid], ib = ri[r][tid + s];
                if (db < da || (db == da && ib < ia)) { rd[r][tid] = db; ri[r][tid] = ib; }
            }
        }
        __syncthreads();
    }
    if (tid < RR) out[row0 + tid] = ri[tid][0];
}

extern "C" void kernel_launch(void* const* d_in, const int* in_sizes, int n_in,
                              void* d_out, int out_size, void* d_ws, size_t ws_size,
                              hipStream_t stream) {
    const float* x      = (const float*)d_in[0];
    const float* w_ih   = (const float*)d_in[1];
    const float* w_hh   = (const float*)d_in[2];
    const float* b_ih   = (const float*)d_in[3];
    const float* b_hh   = (const float*)d_in[4];
    const float* protos = (const float*)d_in[5];
    int* out = (int*)d_out;

    float* ws   = (float*)d_ws;
    float* wTih = ws;                              // 128*768   = 98304 floats
    float* wThh = ws + DD * GG;                    // 256*768   = 196608 floats
    float* pT   = ws + DD * GG + HH * GG;          // 256*2048  = 524288 floats
    // total ws use: 3.28 MB

    hipLaunchKernelGGL(prep_kernel, dim3((HH * PP + 255) / 256), dim3(256), 0, stream,
                       w_ih, w_hh, protos, wTih, wThh, pT);
    hipLaunchKernelGGL(gru_kernel, dim3(BATCH / RR), dim3(256), 0, stream,
                       x, wTih, wThh, b_ih, b_hh, pT, out);
}